// Round 6
// baseline (1093.553 us; speedup 1.0000x reference)
//
#include <hip/hip_runtime.h>
#include <hip/hip_bf16.h>
#include <stdint.h>
#include <math.h>

#define C_DIM 512
#define M_DIM 8192
#define N_TOK 32768
#define MSPLIT 8
#define MARGIN 8e-3f

typedef _Float16 f16;
typedef _Float16 f16x8 __attribute__((ext_vector_type(8)));
typedef float f32x4 __attribute__((ext_vector_type(4)));

// ---------------- codebook column inverse norms (f64 sum; f32 + f64 out) ----
__global__ void k_colnorm(const float* __restrict__ emb, float* __restrict__ inv,
                          double* __restrict__ inv64) {
    int m = blockIdx.x * 256 + threadIdx.x;
    double s = 0.0;
    for (int c = 0; c < C_DIM; ++c) {
        double v = (double)emb[(size_t)c * M_DIM + m];
        s += v * v;
    }
    double r = 1.0 / fmax(sqrt(s), 1e-12);
    inv[m] = (float)r;
    inv64[m] = r;
}

// ---------------- x -> f16 ----------------
__global__ void k_xprep(const float* __restrict__ x, f16* __restrict__ xh) {
    int i = (blockIdx.x * 256 + threadIdx.x) * 8;
    float4 a = *(const float4*)&x[i];
    float4 b = *(const float4*)&x[i + 4];
    f16x8 h;
    h[0] = (f16)a.x; h[1] = (f16)a.y; h[2] = (f16)a.z; h[3] = (f16)a.w;
    h[4] = (f16)b.x; h[5] = (f16)b.y; h[6] = (f16)b.z; h[7] = (f16)b.w;
    *(f16x8*)&xh[i] = h;
}

// ---------------- emb -> transposed f16 + normalized fp32 transposed --------
__global__ void k_eprep(const float* __restrict__ emb, const float* __restrict__ inv,
                        f16* __restrict__ eTh, float* __restrict__ normT) {
    __shared__ float t[32][33];
    int m0 = blockIdx.x * 32, k0 = blockIdx.y * 32;
    int tx = threadIdx.x, ty = threadIdx.y;   // block (32,8)
    for (int r = ty; r < 32; r += 8)
        t[r][tx] = emb[(size_t)(k0 + r) * M_DIM + m0 + tx];
    __syncthreads();
    for (int r = ty; r < 32; r += 8) {
        float v = t[tx][r];            // = emb[k0+tx][m0+r]
        int m = m0 + r;
        eTh[(size_t)m * C_DIM + k0 + tx] = (f16)v;
        normT[(size_t)m * C_DIM + k0 + tx] = v * inv[m];
    }
}

// ---------------- f16 MFMA GEMM + fused per-row top-2 ----------------
// Wave decomposition (race-free): wave wid owns tokens [wid*32, wid*32+32)
// of the 128-token block and ALL 128 codes of each mt tile (fr in [0,2),
// fc in [0,8)). No two waves write the same output row.
__launch_bounds__(256, 2)
__global__ void k_gemm(const f16* __restrict__ xh, const f16* __restrict__ eTh,
                       const float* __restrict__ inv,
                       float* __restrict__ pv1, int* __restrict__ pi1,
                       float* __restrict__ pv2) {
    __shared__ __align__(16) f16 xs[128 * 32];
    __shared__ __align__(16) f16 es[128 * 32];
    const int tid = threadIdx.x;
    const int lane = tid & 63, wid = tid >> 6;
    const int n0 = blockIdx.x * 128;
    const int by = blockIdx.y;
    const int l15 = lane & 15, l4 = lane >> 4;
    const f32x4 ZERO = {0.f, 0.f, 0.f, 0.f};

    float v1[8], v2[8]; int i1[8];
#pragma unroll
    for (int r = 0; r < 8; ++r) { v1[r] = -1e30f; v2[r] = -1e30f; i1[r] = 0; }

    for (int mt = 0; mt < 8; ++mt) {
        const int mbase = by * 1024 + mt * 128;
        f32x4 acc[2][8];
#pragma unroll
        for (int a = 0; a < 2; ++a)
#pragma unroll
            for (int b = 0; b < 8; ++b) acc[a][b] = ZERO;

        for (int kt = 0; kt < 16; ++kt) {
            __syncthreads();
            {
                int L = tid;
#pragma unroll
                for (int it = 0; it < 2; ++it, L += 256) {
                    int row = L >> 2, ch = (L & 3) * 8;
                    *(f16x8*)&xs[row * 32 + ch] =
                        *(const f16x8*)&xh[(size_t)(n0 + row) * C_DIM + kt * 32 + ch];
                    *(f16x8*)&es[row * 32 + ch] =
                        *(const f16x8*)&eTh[(size_t)(mbase + row) * C_DIM + kt * 32 + ch];
                }
            }
            __syncthreads();
            f16x8 A[2];
#pragma unroll
            for (int fr = 0; fr < 2; ++fr)
                A[fr] = *(const f16x8*)&xs[(wid * 32 + fr * 16 + l15) * 32 + l4 * 8];
#pragma unroll
            for (int fc = 0; fc < 8; ++fc) {
                f16x8 B = *(const f16x8*)&es[(fc * 16 + l15) * 32 + l4 * 8];
#pragma unroll
                for (int fr = 0; fr < 2; ++fr)
                    acc[fr][fc] = __builtin_amdgcn_mfma_f32_16x16x32_f16(A[fr], B, acc[fr][fc], 0, 0, 0);
            }
        }
        // epilogue: scale by inv-norm, update running top-2
#pragma unroll
        for (int fc = 0; fc < 8; ++fc) {
            int m = mbase + fc * 16 + l15;
            float iv = inv[m];
#pragma unroll
            for (int fr = 0; fr < 2; ++fr) {
#pragma unroll
                for (int j = 0; j < 4; ++j) {
                    float v = acc[fr][fc][j] * iv;
                    int slot = fr * 4 + j;
                    if (v > v1[slot]) { v2[slot] = v1[slot]; v1[slot] = v; i1[slot] = m; }
                    else if (v > v2[slot]) { v2[slot] = v; }
                }
            }
        }
    }

    // cross-lane (16 lanes hold distinct codes of same token) top-2 merge
#pragma unroll
    for (int slot = 0; slot < 8; ++slot) {
        int fr = slot >> 2, j = slot & 3;
        float v = v1[slot], w = v2[slot]; int ix = i1[slot];
#pragma unroll
        for (int off = 1; off < 16; off <<= 1) {
            float ov = __shfl_xor(v, off);
            int  oix = __shfl_xor(ix, off);
            float ow = __shfl_xor(w, off);
            bool owin = (ov > v) || (ov == v && oix < ix);
            if (owin) { w = fmaxf(v, ow); v = ov; ix = oix; }
            else      { w = fmaxf(w, ov); }
        }
        if (l15 == 0) {
            int n = n0 + wid * 32 + fr * 16 + l4 * 4 + j;
            pv1[(size_t)by * N_TOK + n] = v;
            pi1[(size_t)by * N_TOK + n] = ix;
            pv2[(size_t)by * N_TOK + n] = w;
        }
    }
}

// ---------------- merge MSPLIT partials, flag narrow-gap rows ---------------
__global__ void k_merge_flag(const float* __restrict__ pv1, const int* __restrict__ pi1,
                             const float* __restrict__ pv2,
                             int* __restrict__ best, int* __restrict__ list,
                             int* __restrict__ count) {
    int n = blockIdx.x * 256 + threadIdx.x;
    float v = pv1[n]; int ix = pi1[n]; float w = pv2[n];
    for (int s = 1; s < MSPLIT; ++s) {
        float ov = pv1[(size_t)s * N_TOK + n];
        int  oix = pi1[(size_t)s * N_TOK + n];
        float ow = pv2[(size_t)s * N_TOK + n];
        bool owin = (ov > v) || (ov == v && oix < ix);
        if (owin) { w = fmaxf(v, ow); v = ov; ix = oix; }
        else      { w = fmaxf(w, ov); }
    }
    best[n] = ix;
    if (v - w < MARGIN) {
        int p = atomicAdd(count, 1);
        list[p] = n;
    }
}

// ---------------- exact f64 argmax (rescan of flagged rows / full fallback) -
#define RROWS 16
template <bool IDENT>
__global__ void k_rescan(const float* __restrict__ x, const float* __restrict__ emb,
                         const double* __restrict__ inv64, const int* __restrict__ list,
                         const int* __restrict__ countp,
                         double* __restrict__ prv, int* __restrict__ pri) {
    __shared__ __align__(16) float xsh[RROWS * C_DIM];   // 32 KB
    __shared__ double wred_v[4][RROWS];
    __shared__ int    wred_i[4][RROWS];
    const int tid = threadIdx.x, lane = tid & 63, wid = tid >> 6;
    const int by = blockIdx.y;
    const int cnt = IDENT ? N_TOK : *countp;
    const int ntiles = (cnt + RROWS - 1) / RROWS;

    for (int tile = blockIdx.x; tile < ntiles; tile += gridDim.x) {
        __syncthreads();
        // stage RROWS rows of x (RROWS*128 float4 = 2048 loads, 8 per thread)
        for (int it = 0; it < 8; ++it) {
            int lin = tid + it * 256;
            int row = lin >> 7, c4 = (lin & 127) << 2;
            int p = tile * RROWS + row;
            float4 val = make_float4(0.f, 0.f, 0.f, 0.f);
            if (p < cnt) {
                int n = IDENT ? p : list[p];
                val = *(const float4*)&x[(size_t)n * C_DIM + c4];
            }
            *(float4*)&xsh[row * C_DIM + c4] = val;
        }
        __syncthreads();

        double bv[RROWS]; int bi[RROWS];
#pragma unroll
        for (int i = 0; i < RROWS; ++i) { bv[i] = -1e300; bi[i] = 0; }

        for (int jj = 0; jj < 4; ++jj) {
            const int m = by * 1024 + jj * 256 + tid;
            double acc[RROWS];
#pragma unroll
            for (int i = 0; i < RROWS; ++i) acc[i] = 0.0;
            for (int c = 0; c < C_DIM; c += 4) {
                double b0 = (double)emb[(size_t)(c + 0) * M_DIM + m];
                double b1 = (double)emb[(size_t)(c + 1) * M_DIM + m];
                double b2 = (double)emb[(size_t)(c + 2) * M_DIM + m];
                double b3 = (double)emb[(size_t)(c + 3) * M_DIM + m];
#pragma unroll
                for (int i = 0; i < RROWS; ++i) {
                    float4 a = *(const float4*)&xsh[i * C_DIM + c];
                    acc[i] = fma((double)a.x, b0, fma((double)a.y, b1,
                              fma((double)a.z, b2, fma((double)a.w, b3, acc[i]))));
                }
            }
            double iv = inv64[m];
#pragma unroll
            for (int i = 0; i < RROWS; ++i) {
                double v = acc[i] * iv;
                if (v > bv[i]) { bv[i] = v; bi[i] = m; }
            }
        }
        // reduce across 256 threads per row
#pragma unroll
        for (int i = 0; i < RROWS; ++i) {
            double v = bv[i]; int ix = bi[i];
#pragma unroll
            for (int off = 1; off < 64; off <<= 1) {
                double ov = __shfl_xor(v, off);
                int   oix = __shfl_xor(ix, off);
                if (ov > v || (ov == v && oix < ix)) { v = ov; ix = oix; }
            }
            if (lane == 0) { wred_v[wid][i] = v; wred_i[wid][i] = ix; }
        }
        __syncthreads();
        if (tid < RROWS) {
            int i = tid;
            double v = wred_v[0][i]; int ix = wred_i[0][i];
            for (int wdx = 1; wdx < 4; ++wdx) {
                double ov = wred_v[wdx][i]; int oix = wred_i[wdx][i];
                if (ov > v || (ov == v && oix < ix)) { v = ov; ix = oix; }
            }
            int p = tile * RROWS + i;
            if (p < cnt) {
                prv[(size_t)by * N_TOK + p] = v;
                pri[(size_t)by * N_TOK + p] = ix;
            }
        }
    }
}

// ---------------- merge rescan partials ----------------
template <bool IDENT>
__global__ void k_merge2(const double* __restrict__ prv, const int* __restrict__ pri,
                         const int* __restrict__ list, const int* __restrict__ countp,
                         int* __restrict__ best) {
    int p = blockIdx.x * 256 + threadIdx.x;
    const int cnt = IDENT ? N_TOK : *countp;
    if (p >= cnt) return;
    double v = prv[p]; int ix = pri[p];
    for (int s = 1; s < MSPLIT; ++s) {
        double ov = prv[(size_t)s * N_TOK + p];
        int   oix = pri[(size_t)s * N_TOK + p];
        if (ov > v || (ov == v && oix < ix)) { v = ov; ix = oix; }
    }
    best[IDENT ? p : list[p]] = ix;
}

// ---------------- gather normalized code rows ----------------
__global__ void k_gather(const float* __restrict__ normT, const int* __restrict__ best,
                         float* __restrict__ out) {
    int n = blockIdx.x;
    int b = best[n];
    int c = threadIdx.x * 4;
    *(float4*)&out[(size_t)n * C_DIM + c] = *(const float4*)&normT[(size_t)b * C_DIM + c];
}

__global__ void k_gather_fb(const float* __restrict__ emb, const float* __restrict__ inv,
                            const int* __restrict__ best, float* __restrict__ out) {
    int n = blockIdx.x;
    int b = best[n];
    float iv = inv[b];
    for (int c = threadIdx.x; c < C_DIM; c += 128)
        out[(size_t)n * C_DIM + c] = emb[(size_t)c * M_DIM + b] * iv;
}

// ---------------- host ----------------
extern "C" void kernel_launch(void* const* d_in, const int* in_sizes, int n_in,
                              void* d_out, int out_size, void* d_ws, size_t ws_size,
                              hipStream_t stream) {
    const float* x   = (const float*)d_in[0];
    const float* emb = (const float*)d_in[1];
    float* out = (float*)d_out;
    char* ws = (char*)d_ws;

    // primary layout (~62.3 MB)
    float*  inv   = (float*) (ws + 0);          //  32 KB
    double* inv64 = (double*)(ws + 32768);      //  64 KB
    f16*    xh    = (f16*)   (ws + 98304);      //  32 MB
    f16*    eTh   = (f16*)   (ws + 33652736);   //   8 MB
    float*  normT = (float*) (ws + 42041344);   //  16 MB
    float*  pv1   = (float*) (ws + 58818560);   //   1 MB
    int*    pi1   = (int*)   (ws + 59867136);   //   1 MB
    float*  pv2   = (float*) (ws + 60915712);   //   1 MB
    int*    best  = (int*)   (ws + 61964288);   // 128 KB
    int*    list  = (int*)   (ws + 62095360);   // 128 KB
    int*    count = (int*)   (ws + 62226432);   // 256 B
    double* prv   = (double*)(ws + 62226688);   //   2 MB
    int*    pri   = (int*)   (ws + 64323840);   //   1 MB
    const size_t NEED = 65372416;

    if (ws_size >= NEED) {
        hipMemsetAsync(count, 0, 4, stream);
        k_colnorm<<<M_DIM / 256, 256, 0, stream>>>(emb, inv, inv64);
        k_xprep<<<(N_TOK * C_DIM) / (256 * 8), 256, 0, stream>>>(x, xh);
        k_eprep<<<dim3(M_DIM / 32, C_DIM / 32), dim3(32, 8), 0, stream>>>(emb, inv, eTh, normT);
        k_gemm<<<dim3(N_TOK / 128, MSPLIT), 256, 0, stream>>>(xh, eTh, inv, pv1, pi1, pv2);
        k_merge_flag<<<N_TOK / 256, 256, 0, stream>>>(pv1, pi1, pv2, best, list, count);
        k_rescan<false><<<dim3(64, MSPLIT), 256, 0, stream>>>(x, emb, inv64, list, count, prv, pri);
        k_merge2<false><<<N_TOK / 256, 256, 0, stream>>>(prv, pri, list, count, best);
        k_gather<<<N_TOK, 128, 0, stream>>>(normT, best, out);
    } else {
        // fallback: exact f64 everywhere, minimal ws (~3.4 MB)
        float*  f_inv   = (float*) (ws + 0);
        double* f_inv64 = (double*)(ws + 32768);
        double* f_prv   = (double*)(ws + 98304);
        int*    f_pri   = (int*)   (ws + 2195456);
        int*    f_best  = (int*)   (ws + 3244032);
        k_colnorm<<<M_DIM / 256, 256, 0, stream>>>(emb, f_inv, f_inv64);
        k_rescan<true><<<dim3(256, MSPLIT), 256, 0, stream>>>(x, emb, f_inv64, nullptr, nullptr, f_prv, f_pri);
        k_merge2<true><<<N_TOK / 256, 256, 0, stream>>>(f_prv, f_pri, nullptr, nullptr, f_best);
        k_gather_fb<<<N_TOK, 128, 0, stream>>>(emb, f_inv, f_best, out);
    }
}

// Round 7
// 1074.626 us; speedup vs baseline: 1.0176x; 1.0176x over previous
//
#include <hip/hip_runtime.h>
#include <hip/hip_bf16.h>
#include <stdint.h>
#include <math.h>

#define C_DIM 512
#define M_DIM 8192
#define N_TOK 32768
#define MSPLIT 8
#define MARGIN 5e-3f

typedef _Float16 f16;
typedef _Float16 f16x8 __attribute__((ext_vector_type(8)));
typedef float f32x4 __attribute__((ext_vector_type(4)));

typedef const __attribute__((address_space(1))) void gas_void;
typedef __attribute__((address_space(3))) void las_void;

// async 16B/lane global->LDS; lds dest must be the wave-uniform base
__device__ __forceinline__ void gl16(const void* g, void* l) {
    __builtin_amdgcn_global_load_lds((gas_void*)g, (las_void*)l, 16, 0, 0);
}

// ---------------- codebook column inverse norms (f64 sum; f32 + f64 out) ----
__global__ void k_colnorm(const float* __restrict__ emb, float* __restrict__ inv,
                          double* __restrict__ inv64) {
    int m = blockIdx.x * 256 + threadIdx.x;
    double s = 0.0;
    for (int c = 0; c < C_DIM; ++c) {
        double v = (double)emb[(size_t)c * M_DIM + m];
        s += v * v;
    }
    double r = 1.0 / fmax(sqrt(s), 1e-12);
    inv[m] = (float)r;
    inv64[m] = r;
}

// ---------------- x -> f16 ----------------
__global__ void k_xprep(const float* __restrict__ x, f16* __restrict__ xh) {
    int i = (blockIdx.x * 256 + threadIdx.x) * 8;
    float4 a = *(const float4*)&x[i];
    float4 b = *(const float4*)&x[i + 4];
    f16x8 h;
    h[0] = (f16)a.x; h[1] = (f16)a.y; h[2] = (f16)a.z; h[3] = (f16)a.w;
    h[4] = (f16)b.x; h[5] = (f16)b.y; h[6] = (f16)b.z; h[7] = (f16)b.w;
    *(f16x8*)&xh[i] = h;
}

// ---------------- emb -> transposed f16 + normalized fp32 transposed --------
__global__ void k_eprep(const float* __restrict__ emb, const float* __restrict__ inv,
                        f16* __restrict__ eTh, float* __restrict__ normT) {
    __shared__ float t[32][33];
    int m0 = blockIdx.x * 32, k0 = blockIdx.y * 32;
    int tx = threadIdx.x, ty = threadIdx.y;   // block (32,8)
    for (int r = ty; r < 32; r += 8)
        t[r][tx] = emb[(size_t)(k0 + r) * M_DIM + m0 + tx];
    __syncthreads();
    for (int r = ty; r < 32; r += 8) {
        float v = t[tx][r];            // = emb[k0+tx][m0+r]
        int m = m0 + r;
        eTh[(size_t)m * C_DIM + k0 + tx] = (f16)v;
        normT[(size_t)m * C_DIM + k0 + tx] = v * inv[m];
    }
}

// ---------------- f16 MFMA GEMM + fused per-row top-2 ----------------
// Wave wid owns tokens [wid*32, wid*32+32) x ALL 128 codes per mt tile.
// Staging: global_load_lds width-16, linear LDS dest (byte = L*16), with the
// XOR swizzle swz(b) = b ^ (((b>>7)&3)<<4) applied on the per-lane global
// SOURCE slot and on the ds_read addresses (rule: linear dest + inv-swz
// source + swz read). Breaks the 8-way bank conflict of 64B-stride rows.
__launch_bounds__(256, 2)
__global__ void k_gemm(const f16* __restrict__ xh, const f16* __restrict__ eTh,
                       const float* __restrict__ inv,
                       float* __restrict__ pv1, int* __restrict__ pi1,
                       float* __restrict__ pv2) {
    __shared__ __align__(16) f16 xs[128 * 32];
    __shared__ __align__(16) f16 es[128 * 32];
    const int tid = threadIdx.x;
    const int lane = tid & 63, wid = tid >> 6;
    const int n0 = blockIdx.x * 128;
    const int by = blockIdx.y;
    const int l15 = lane & 15, l4 = lane >> 4;
    const f32x4 ZERO = {0.f, 0.f, 0.f, 0.f};

    // per-lane global source element offsets (swizzled slot), L = tid, tid+256
    const int row0 = tid >> 2,        slot0 = (tid & 3) ^ ((tid >> 3) & 3);
    const int row1 = (tid + 256) >> 2, slot1 = (tid & 3) ^ (((tid + 256) >> 3) & 3);
    const int so0 = row0 * C_DIM + slot0 * 8;
    const int so1 = row1 * C_DIM + slot1 * 8;
    // wave-uniform LDS dest bases (bytes)
    char* xsb = (char*)xs; char* esb = (char*)es;
    char* xd0 = xsb + wid * 1024; char* xd1 = xsb + 4096 + wid * 1024;
    char* ed0 = esb + wid * 1024; char* ed1 = esb + 4096 + wid * 1024;

    // precomputed swizzled fragment read offsets (bytes)
    int aoff[2], boff[8];
#pragma unroll
    for (int fr = 0; fr < 2; ++fr) {
        int r = wid * 32 + fr * 16 + l15;
        aoff[fr] = (r * 64 + l4 * 16) ^ (((r >> 1) & 3) << 4);
    }
#pragma unroll
    for (int fc = 0; fc < 8; ++fc) {
        int r = fc * 16 + l15;
        boff[fc] = (r * 64 + l4 * 16) ^ (((r >> 1) & 3) << 4);
    }

    const f16* xp0 = xh + (size_t)n0 * C_DIM + so0;
    const f16* xp1 = xh + (size_t)n0 * C_DIM + so1;

    float v1[8], v2[8]; int i1[8];
#pragma unroll
    for (int r = 0; r < 8; ++r) { v1[r] = -1e30f; v2[r] = -1e30f; i1[r] = 0; }

    for (int mt = 0; mt < 8; ++mt) {
        const int mbase = by * 1024 + mt * 128;
        const f16* ep0 = eTh + (size_t)mbase * C_DIM + so0;
        const f16* ep1 = eTh + (size_t)mbase * C_DIM + so1;
        f32x4 acc[2][8];
#pragma unroll
        for (int a = 0; a < 2; ++a)
#pragma unroll
            for (int b = 0; b < 8; ++b) acc[a][b] = ZERO;

        for (int kt = 0; kt < 16; ++kt) {
            __syncthreads();            // prior readers done before overwrite
            gl16(xp0 + kt * 32, xd0);
            gl16(xp1 + kt * 32, xd1);
            gl16(ep0 + kt * 32, ed0);
            gl16(ep1 + kt * 32, ed1);
            __syncthreads();            // vmcnt(0) drain before reads
            f16x8 A[2];
#pragma unroll
            for (int fr = 0; fr < 2; ++fr)
                A[fr] = *(const f16x8*)(xsb + aoff[fr]);
#pragma unroll
            for (int fc = 0; fc < 8; ++fc) {
                f16x8 B = *(const f16x8*)(esb + boff[fc]);
#pragma unroll
                for (int fr = 0; fr < 2; ++fr)
                    acc[fr][fc] = __builtin_amdgcn_mfma_f32_16x16x32_f16(A[fr], B, acc[fr][fc], 0, 0, 0);
            }
        }
        // epilogue: scale by inv-norm, update running top-2
#pragma unroll
        for (int fc = 0; fc < 8; ++fc) {
            int m = mbase + fc * 16 + l15;
            float iv = inv[m];
#pragma unroll
            for (int fr = 0; fr < 2; ++fr) {
#pragma unroll
                for (int j = 0; j < 4; ++j) {
                    float v = acc[fr][fc][j] * iv;
                    int slot = fr * 4 + j;
                    if (v > v1[slot]) { v2[slot] = v1[slot]; v1[slot] = v; i1[slot] = m; }
                    else if (v > v2[slot]) { v2[slot] = v; }
                }
            }
        }
    }

    // cross-lane (16 lanes hold distinct codes of same token) top-2 merge
#pragma unroll
    for (int slot = 0; slot < 8; ++slot) {
        int fr = slot >> 2, j = slot & 3;
        float v = v1[slot], w = v2[slot]; int ix = i1[slot];
#pragma unroll
        for (int off = 1; off < 16; off <<= 1) {
            float ov = __shfl_xor(v, off);
            int  oix = __shfl_xor(ix, off);
            float ow = __shfl_xor(w, off);
            bool owin = (ov > v) || (ov == v && oix < ix);
            if (owin) { w = fmaxf(v, ow); v = ov; ix = oix; }
            else      { w = fmaxf(w, ov); }
        }
        if (l15 == 0) {
            int n = n0 + wid * 32 + fr * 16 + l4 * 4 + j;
            pv1[(size_t)by * N_TOK + n] = v;
            pi1[(size_t)by * N_TOK + n] = ix;
            pv2[(size_t)by * N_TOK + n] = w;
        }
    }
}

// ---------------- merge MSPLIT partials, flag narrow-gap rows ---------------
__global__ void k_merge_flag(const float* __restrict__ pv1, const int* __restrict__ pi1,
                             const float* __restrict__ pv2,
                             int* __restrict__ best, int* __restrict__ list,
                             int* __restrict__ count) {
    int n = blockIdx.x * 256 + threadIdx.x;
    float v = pv1[n]; int ix = pi1[n]; float w = pv2[n];
    for (int s = 1; s < MSPLIT; ++s) {
        float ov = pv1[(size_t)s * N_TOK + n];
        int  oix = pi1[(size_t)s * N_TOK + n];
        float ow = pv2[(size_t)s * N_TOK + n];
        bool owin = (ov > v) || (ov == v && oix < ix);
        if (owin) { w = fmaxf(v, ow); v = ov; ix = oix; }
        else      { w = fmaxf(w, ov); }
    }
    best[n] = ix;
    if (v - w < MARGIN) {
        int p = atomicAdd(count, 1);
        list[p] = n;
    }
}

// ---------------- exact f64 argmax (rescan of flagged rows / full fallback) -
#define RROWS 16
template <bool IDENT>
__global__ void k_rescan(const float* __restrict__ x, const float* __restrict__ emb,
                         const double* __restrict__ inv64, const int* __restrict__ list,
                         const int* __restrict__ countp,
                         double* __restrict__ prv, int* __restrict__ pri) {
    __shared__ __align__(16) float xsh[RROWS * C_DIM];   // 32 KB
    __shared__ double wred_v[4][RROWS];
    __shared__ int    wred_i[4][RROWS];
    const int tid = threadIdx.x, lane = tid & 63, wid = tid >> 6;
    const int by = blockIdx.y;
    const int cnt = IDENT ? N_TOK : *countp;
    const int ntiles = (cnt + RROWS - 1) / RROWS;

    for (int tile = blockIdx.x; tile < ntiles; tile += gridDim.x) {
        __syncthreads();
        for (int it = 0; it < 8; ++it) {
            int lin = tid + it * 256;
            int row = lin >> 7, c4 = (lin & 127) << 2;
            int p = tile * RROWS + row;
            float4 val = make_float4(0.f, 0.f, 0.f, 0.f);
            if (p < cnt) {
                int n = IDENT ? p : list[p];
                val = *(const float4*)&x[(size_t)n * C_DIM + c4];
            }
            *(float4*)&xsh[row * C_DIM + c4] = val;
        }
        __syncthreads();

        double bv[RROWS]; int bi[RROWS];
#pragma unroll
        for (int i = 0; i < RROWS; ++i) { bv[i] = -1e300; bi[i] = 0; }

        for (int jj = 0; jj < 4; ++jj) {
            const int m = by * 1024 + jj * 256 + tid;
            double acc[RROWS];
#pragma unroll
            for (int i = 0; i < RROWS; ++i) acc[i] = 0.0;
            for (int c = 0; c < C_DIM; c += 4) {
                double b0 = (double)emb[(size_t)(c + 0) * M_DIM + m];
                double b1 = (double)emb[(size_t)(c + 1) * M_DIM + m];
                double b2 = (double)emb[(size_t)(c + 2) * M_DIM + m];
                double b3 = (double)emb[(size_t)(c + 3) * M_DIM + m];
#pragma unroll
                for (int i = 0; i < RROWS; ++i) {
                    float4 a = *(const float4*)&xsh[i * C_DIM + c];
                    acc[i] = fma((double)a.x, b0, fma((double)a.y, b1,
                              fma((double)a.z, b2, fma((double)a.w, b3, acc[i]))));
                }
            }
            double iv = inv64[m];
#pragma unroll
            for (int i = 0; i < RROWS; ++i) {
                double v = acc[i] * iv;
                if (v > bv[i]) { bv[i] = v; bi[i] = m; }
            }
        }
#pragma unroll
        for (int i = 0; i < RROWS; ++i) {
            double v = bv[i]; int ix = bi[i];
#pragma unroll
            for (int off = 1; off < 64; off <<= 1) {
                double ov = __shfl_xor(v, off);
                int   oix = __shfl_xor(ix, off);
                if (ov > v || (ov == v && oix < ix)) { v = ov; ix = oix; }
            }
            if (lane == 0) { wred_v[wid][i] = v; wred_i[wid][i] = ix; }
        }
        __syncthreads();
        if (tid < RROWS) {
            int i = tid;
            double v = wred_v[0][i]; int ix = wred_i[0][i];
            for (int wdx = 1; wdx < 4; ++wdx) {
                double ov = wred_v[wdx][i]; int oix = wred_i[wdx][i];
                if (ov > v || (ov == v && oix < ix)) { v = ov; ix = oix; }
            }
            int p = tile * RROWS + i;
            if (p < cnt) {
                prv[(size_t)by * N_TOK + p] = v;
                pri[(size_t)by * N_TOK + p] = ix;
            }
        }
    }
}

// ---------------- merge rescan partials ----------------
template <bool IDENT>
__global__ void k_merge2(const double* __restrict__ prv, const int* __restrict__ pri,
                         const int* __restrict__ list, const int* __restrict__ countp,
                         int* __restrict__ best) {
    int p = blockIdx.x * 256 + threadIdx.x;
    const int cnt = IDENT ? N_TOK : *countp;
    if (p >= cnt) return;
    double v = prv[p]; int ix = pri[p];
    for (int s = 1; s < MSPLIT; ++s) {
        double ov = prv[(size_t)s * N_TOK + p];
        int   oix = pri[(size_t)s * N_TOK + p];
        if (ov > v || (ov == v && oix < ix)) { v = ov; ix = oix; }
    }
    best[IDENT ? p : list[p]] = ix;
}

// ---------------- gather normalized code rows ----------------
__global__ void k_gather(const float* __restrict__ normT, const int* __restrict__ best,
                         float* __restrict__ out) {
    int n = blockIdx.x;
    int b = best[n];
    int c = threadIdx.x * 4;
    *(float4*)&out[(size_t)n * C_DIM + c] = *(const float4*)&normT[(size_t)b * C_DIM + c];
}

__global__ void k_gather_fb(const float* __restrict__ emb, const float* __restrict__ inv,
                            const int* __restrict__ best, float* __restrict__ out) {
    int n = blockIdx.x;
    int b = best[n];
    float iv = inv[b];
    for (int c = threadIdx.x; c < C_DIM; c += 128)
        out[(size_t)n * C_DIM + c] = emb[(size_t)c * M_DIM + b] * iv;
}

// ---------------- host ----------------
extern "C" void kernel_launch(void* const* d_in, const int* in_sizes, int n_in,
                              void* d_out, int out_size, void* d_ws, size_t ws_size,
                              hipStream_t stream) {
    const float* x   = (const float*)d_in[0];
    const float* emb = (const float*)d_in[1];
    float* out = (float*)d_out;
    char* ws = (char*)d_ws;

    // primary layout (~62.3 MB)
    float*  inv   = (float*) (ws + 0);          //  32 KB
    double* inv64 = (double*)(ws + 32768);      //  64 KB
    f16*    xh    = (f16*)   (ws + 98304);      //  32 MB
    f16*    eTh   = (f16*)   (ws + 33652736);   //   8 MB
    float*  normT = (float*) (ws + 42041344);   //  16 MB
    float*  pv1   = (float*) (ws + 58818560);   //   1 MB
    int*    pi1   = (int*)   (ws + 59867136);   //   1 MB
    float*  pv2   = (float*) (ws + 60915712);   //   1 MB
    int*    best  = (int*)   (ws + 61964288);   // 128 KB
    int*    list  = (int*)   (ws + 62095360);   // 128 KB
    int*    count = (int*)   (ws + 62226432);   // 256 B
    double* prv   = (double*)(ws + 62226688);   //   2 MB
    int*    pri   = (int*)   (ws + 64323840);   //   1 MB
    const size_t NEED = 65372416;

    if (ws_size >= NEED) {
        hipMemsetAsync(count, 0, 4, stream);
        k_colnorm<<<M_DIM / 256, 256, 0, stream>>>(emb, inv, inv64);
        k_xprep<<<(N_TOK * C_DIM) / (256 * 8), 256, 0, stream>>>(x, xh);
        k_eprep<<<dim3(M_DIM / 32, C_DIM / 32), dim3(32, 8), 0, stream>>>(emb, inv, eTh, normT);
        k_gemm<<<dim3(N_TOK / 128, MSPLIT), 256, 0, stream>>>(xh, eTh, inv, pv1, pi1, pv2);
        k_merge_flag<<<N_TOK / 256, 256, 0, stream>>>(pv1, pi1, pv2, best, list, count);
        k_rescan<false><<<dim3(64, MSPLIT), 256, 0, stream>>>(x, emb, inv64, list, count, prv, pri);
        k_merge2<false><<<N_TOK / 256, 256, 0, stream>>>(prv, pri, list, count, best);
        k_gather<<<N_TOK, 128, 0, stream>>>(normT, best, out);
    } else {
        // fallback: exact f64 everywhere, minimal ws (~3.4 MB)
        float*  f_inv   = (float*) (ws + 0);
        double* f_inv64 = (double*)(ws + 32768);
        double* f_prv   = (double*)(ws + 98304);
        int*    f_pri   = (int*)   (ws + 2195456);
        int*    f_best  = (int*)   (ws + 3244032);
        k_colnorm<<<M_DIM / 256, 256, 0, stream>>>(emb, f_inv, f_inv64);
        k_rescan<true><<<dim3(256, MSPLIT), 256, 0, stream>>>(x, emb, f_inv64, nullptr, nullptr, f_prv, f_pri);
        k_merge2<true><<<N_TOK / 256, 256, 0, stream>>>(f_prv, f_pri, nullptr, nullptr, f_best);
        k_gather_fb<<<N_TOK, 128, 0, stream>>>(emb, f_inv, f_best, out);
    }
}